// Round 8
// baseline (872.252 us; speedup 1.0000x reference)
//
#include <hip/hip_runtime.h>
#include <hip/hip_bf16.h>

#define N_NODES 100000
#define F_IN    256
#define H_DIM   128
#define C_CLS   16
#define NBKT    13            // src buckets (slices of 8192 rows = 2 MB bf16)
#define BSH     13            // bucket = src >> 13
#define SLICE   8192
#define NBINS   (N_NODES * NBKT)          // 1,300,000
#define SB1     ((NBINS + 255) / 256)     // scan blocks over bins
#define NPW     32            // nodes per wave in gcn_bucket
#define GBLK    800           // gcn_bucket blocks (3200 waves * 32 = 102400 >= N)

typedef __attribute__((ext_vector_type(8))) short  short8;
typedef __attribute__((ext_vector_type(4))) float  float4v;
typedef __attribute__((ext_vector_type(4))) unsigned short ushort4v;

__device__ __forceinline__ float b2f(ushort u) {
    union { unsigned int i; float f; } v;
    v.i = ((unsigned int)u) << 16;
    return v.f;
}

__device__ __forceinline__ ushort f2b(float f) {
    unsigned int x = __float_as_uint(f);
    unsigned int r = (x + 0x7FFFu + ((x >> 16) & 1u)) >> 16;   // RNE
    return (ushort)r;
}

__device__ __forceinline__ float ldsel(const void* p, int i, int f32f) {
    return f32f ? ((const float*)p)[i] : b2f(((const ushort*)p)[i]);
}

// ------------------------------------------------------------------ sniff ---
__global__ __launch_bounds__(64) void sniff(const ushort* __restrict__ x,
                                            const int* __restrict__ ei,
                                            int* __restrict__ flags) {
    int lane = threadIdx.x;
    int cnt_bf = 0;
#pragma unroll
    for (int j = 0; j < 4; ++j) {
        ushort u = x[lane * 4 + j];
        int e = (u >> 7) & 0xFF;
        if ((e >= 100 && e <= 140) || (u & 0x7FFF) == 0) cnt_bf++;
    }
    int zodd = (ei[2 * lane + 1] == 0) ? 1 : 0;
#pragma unroll
    for (int off = 32; off >= 1; off >>= 1) {
        cnt_bf += __shfl_xor(cnt_bf, off, 64);
        zodd   += __shfl_xor(zodd,   off, 64);
    }
    if (lane == 0) {
        flags[0] = (cnt_bf < 230) ? 1 : 0;   // f32 inputs
        flags[1] = (zodd  >= 32) ? 1 : 0;    // int64 indices
    }
}

// ---------------------- prep: ei -> int32 src/dst + per-(dst,bucket) count --
__global__ __launch_bounds__(256) void prep(const int* __restrict__ flags,
                                            const int* __restrict__ ei,
                                            int* __restrict__ src32,
                                            int* __restrict__ dst32,
                                            int* __restrict__ cnt, int E) {
    int e = blockIdx.x * 256 + threadIdx.x;
    if (e >= E) return;
    int i64 = flags[1];
    int s = i64 ? ei[2L * e]          : ei[e];
    int d = i64 ? ei[2L * E + 2L * e] : ei[(long)E + e];
    src32[e] = s;
    dst32[e] = d;
    atomicAdd(&cnt[d * NBKT + (s >> BSH)], 1);
}

// ------------------------------------------------------------ 3-step scan ---
__global__ __launch_bounds__(256) void scan1(const int* __restrict__ cnt,
                                             int* __restrict__ offs,
                                             int* __restrict__ bsum, int M) {
    __shared__ int sd[256];
    int t = threadIdx.x;
    int i = blockIdx.x * 256 + t;
    int v = (i < M) ? cnt[i] : 0;
    sd[t] = v;
    __syncthreads();
#pragma unroll
    for (int d = 1; d < 256; d <<= 1) {
        int add = (t >= d) ? sd[t - d] : 0;
        __syncthreads();
        sd[t] += add;
        __syncthreads();
    }
    if (i < M) offs[i] = sd[t] - v;          // exclusive within block
    if (t == 255) bsum[blockIdx.x] = sd[255];
}

// single block, chunked serial scan with carry (handles SB1 ~ 5079)
__global__ __launch_bounds__(512) void scan2big(const int* __restrict__ bsum,
                                                int* __restrict__ boff, int M) {
    __shared__ int sd[512];
    __shared__ int carry;
    int t = threadIdx.x;
    if (t == 0) carry = 0;
    __syncthreads();
    for (int base = 0; base < M; base += 512) {
        int i = base + t;
        int v = (i < M) ? bsum[i] : 0;
        sd[t] = v;
        __syncthreads();
#pragma unroll
        for (int d = 1; d < 512; d <<= 1) {
            int add = (t >= d) ? sd[t - d] : 0;
            __syncthreads();
            sd[t] += add;
            __syncthreads();
        }
        int c = carry;
        if (i < M) boff[i] = c + sd[t] - v;   // exclusive
        __syncthreads();
        if (t == 511) carry = c + sd[511];
        __syncthreads();
    }
}

__global__ __launch_bounds__(256) void scan3big(int* __restrict__ offs,
                                                const int* __restrict__ boff,
                                                int* __restrict__ cursor,
                                                int E) {
    int i = blockIdx.x * 256 + threadIdx.x;
    if (i == 0) offs[NBINS] = E;
    if (i >= NBINS) return;
    int off = offs[i] + boff[i >> 8];
    offs[i] = off;
    cursor[i] = off;
}

// ---------------------------------------------------- dis from bin offsets --
__global__ __launch_bounds__(256) void disk(const int* __restrict__ offs2,
                                            float* __restrict__ dis) {
    int n = blockIdx.x * 256 + threadIdx.x;
    if (n < N_NODES) {
        int deg = offs2[(n + 1) * NBKT] - offs2[n * NBKT];
        dis[n] = rsqrtf((float)(deg + 1));      // +1 self-loop
    }
}

// ------------------------------------------------------ permutation build ---
__global__ __launch_bounds__(256) void build_perm(const int* __restrict__ src32,
                                                  const int* __restrict__ dst32,
                                                  const float* __restrict__ dis,
                                                  int* __restrict__ cursor,
                                                  int2* __restrict__ perm2, int E) {
    int e = blockIdx.x * 256 + threadIdx.x;
    if (e >= E) return;
    int s = src32[e];
    int d = dst32[e];
    int slot = atomicAdd(&cursor[d * NBKT + (s >> BSH)], 1);
    perm2[slot] = make_int2(s, __float_as_int(dis[s]));
}

// -------------------------------------------------------------- h = x @ W ---
__global__ __launch_bounds__(256) void gemm_xw(const int* __restrict__ flags,
                                               const ushort* __restrict__ x_b,
                                               const float* __restrict__ x_f,
                                               const ushort* __restrict__ W_b,
                                               const float* __restrict__ W_f,
                                               ushort* __restrict__ hout) {
    __shared__ __align__(16) ushort wt[128][128 + 8];   // 34816 B
    const int f32f = flags[0];

    const int tid  = threadIdx.x;
    const int lane = tid & 63;
    const int wave = tid >> 6;
    const int quad = lane >> 4;
    const int lm   = lane & 15;

    const int rbase = blockIdx.x * 64 + wave * 16;
    int arow = rbase + lm;
    if (arow >= N_NODES) arow = N_NODES - 1;      // clamp; store is guarded

    float4v acc[8];
#pragma unroll
    for (int c = 0; c < 8; ++c) acc[c] = (float4v){0.f, 0.f, 0.f, 0.f};

    for (int hh = 0; hh < 2; ++hh) {
        if (hh) __syncthreads();
#pragma unroll
        for (int it = 0; it < 8; ++it) {
            int flat = (it * 256 + tid) * 8;       // 0..16384
            int kl = flat >> 7;
            int c0 = flat & 127;
            if (!f32f) {
                short8 v = *(const short8*)(W_b + hh * 16384 + flat);
#pragma unroll
                for (int j = 0; j < 8; ++j) wt[c0 + j][kl] = (ushort)v[j];
            } else {
                float4 a = *(const float4*)(W_f + hh * 16384 + flat);
                float4 b = *(const float4*)(W_f + hh * 16384 + flat + 4);
                wt[c0 + 0][kl] = f2b(a.x); wt[c0 + 1][kl] = f2b(a.y);
                wt[c0 + 2][kl] = f2b(a.z); wt[c0 + 3][kl] = f2b(a.w);
                wt[c0 + 4][kl] = f2b(b.x); wt[c0 + 5][kl] = f2b(b.y);
                wt[c0 + 6][kl] = f2b(b.z); wt[c0 + 7][kl] = f2b(b.w);
            }
        }
        __syncthreads();
#pragma unroll
        for (int s = 0; s < 4; ++s) {
            int klocal = s * 32 + quad * 8;
            short8 afrag;
            if (!f32f) {
                afrag = *(const short8*)(x_b + (size_t)arow * F_IN + hh * 128 + klocal);
            } else {
                const float* xr = x_f + (size_t)arow * F_IN + hh * 128 + klocal;
                float4 a = *(const float4*)xr;
                float4 b = *(const float4*)(xr + 4);
                afrag[0] = (short)f2b(a.x); afrag[1] = (short)f2b(a.y);
                afrag[2] = (short)f2b(a.z); afrag[3] = (short)f2b(a.w);
                afrag[4] = (short)f2b(b.x); afrag[5] = (short)f2b(b.y);
                afrag[6] = (short)f2b(b.z); afrag[7] = (short)f2b(b.w);
            }
#pragma unroll
            for (int c = 0; c < 8; ++c) {
                short8 bfrag = *(const short8*)(&wt[c * 16 + lm][klocal]);
                acc[c] = __builtin_amdgcn_mfma_f32_16x16x32_bf16(afrag, bfrag, acc[c], 0, 0, 0);
            }
        }
    }
    // D[row=quad*4+r][col=lane&15]
#pragma unroll
    for (int c = 0; c < 8; ++c) {
        int col = c * 16 + lm;
#pragma unroll
        for (int r = 0; r < 4; ++r) {
            int node = rbase + quad * 4 + r;
            if (node < N_NODES) hout[(size_t)node * H_DIM + col] = f2b(acc[c][r]);
        }
    }
}

// --------------------- bucketed persistent gather (L2-slice locality) -------
// 800 blocks fully resident (3/SIMD cap). Wave owns 32 nodes, register
// accumulators. Per src-bucket: (1) stream-warm this XCD's L2 with the 2MB
// hb slice (chunk rank via blockIdx&7 round-robin XCD mapping), (2) gather
// the 32 nodes' bucket edges — now L2 hits. Static 16-node x 4-round slot
// grid, scalar w!=0 masking, 16-deep load buffer. Raw sums -> agg.
__global__ __launch_bounds__(256, 3) void gcn_bucket(const int* __restrict__ offs2,
                                                     const int2* __restrict__ perm2,
                                                     const ushort* __restrict__ hb,
                                                     float* __restrict__ agg,
                                                     uint* __restrict__ sinkbuf,
                                                     int E) {
    const int tid  = threadIdx.x;
    const int lane = tid & 63;
    const int wvb  = tid >> 6;
    const int gw   = blockIdx.x * 4 + wvb;
    const int base = gw * NPW;
    const int wchunk = (blockIdx.x >> 3) * 4 + wvb;   // rank within XCD group [0,400)

    float ax[NPW], ay[NPW];
#pragma unroll
    for (int n = 0; n < NPW; ++n) { ax[n] = 0.f; ay[n] = 0.f; }

    uint sink = 0;

    for (int b = 0; b < NBKT; ++b) {
        // ---- warm: stream 21 rows of slice b into this XCD's L2 ----
        int sl_end = (b + 1) * SLICE; if (sl_end > N_NODES) sl_end = N_NODES;
        int row0 = b * SLICE + wchunk * 21;
#pragma unroll 1
        for (int rr = 0; rr < 21; ++rr) {
            int row = row0 + rr;
            if (row < sl_end)
                sink ^= *((const uint*)(hb + (size_t)row * H_DIM) + lane);
        }
        // ---- segment bounds for my 32 nodes (lanes 0..31) ----
        int st_l = 0, len_l = 0;
        if (lane < NPW) {
            int nd = base + lane;
            if (nd < N_NODES) {
                int i0 = nd * NBKT + b;
                st_l  = offs2[i0];
                len_l = offs2[i0 + 1] - st_l;
            }
        }
        // per-16-lane-group max length
        int gm = len_l;
        gm = max(gm, __shfl_xor(gm, 8, 64));
        gm = max(gm, __shfl_xor(gm, 4, 64));
        gm = max(gm, __shfl_xor(gm, 2, 64));
        gm = max(gm, __shfl_xor(gm, 1, 64));
        int gmax0 = __builtin_amdgcn_readlane(gm, 0);
        int gmax1 = __builtin_amdgcn_readlane(gm, 16);

#pragma unroll
        for (int g = 0; g < 2; ++g) {
            int gmax = g ? gmax1 : gmax0;
            for (int rb = 0; rb < gmax; rb += 4) {
                // lane j -> slot (node g*16+(j&15), round rb+(j>>4))
                int nsl = g * 16 + (lane & 15);
                int rsl = rb + (lane >> 4);
                int stn = __shfl(st_l, nsl, 64);
                int lnn = __shfl(len_l, nsl, 64);
                bool act = rsl < lnn;
                int pidx = stn + (act ? rsl : 0);
                if (pidx >= E) pidx = E - 1;           // safety clamp
                int2 pr = perm2[pidx];
                int wvi = act ? pr.y : 0;              // w bits (0 if masked)
                int svi = pr.x;
#pragma unroll
                for (int rr = 0; rr < 4; ++rr) {
                    if (rb + rr >= gmax) break;        // wave-uniform
                    int wki[16], ski[16];
#pragma unroll
                    for (int n = 0; n < 16; ++n) {
                        wki[n] = __builtin_amdgcn_readlane(wvi, rr * 16 + n);
                        ski[n] = __builtin_amdgcn_readlane(svi, rr * 16 + n);
                    }
                    uint u[16];
#pragma unroll
                    for (int n = 0; n < 16; ++n)
                        if (wki[n] != 0)
                            u[n] = *((const uint*)(hb + (size_t)ski[n] * H_DIM) + lane);
#pragma unroll
                    for (int n = 0; n < 16; ++n)
                        if (wki[n] != 0) {
                            float w = __int_as_float(wki[n]);
                            ax[g * 16 + n] = fmaf(w, __uint_as_float(u[n] << 16), ax[g * 16 + n]);
                            ay[g * 16 + n] = fmaf(w, __uint_as_float(u[n] & 0xFFFF0000u), ay[g * 16 + n]);
                        }
                }
            }
        }
    }

    // keep warm loads alive (never true at runtime; opaque to compiler)
    if (sink == 0x9E3779B9u && lane == 63 && blockIdx.x > 1000000)
        sinkbuf[0] = sink;

    // store raw sums
#pragma unroll
    for (int n = 0; n < NPW; ++n) {
        int node = base + n;
        if (node < N_NODES) {
            float2 v; v.x = ax[n]; v.y = ay[n];
            *(float2*)(agg + (size_t)node * H_DIM + 2 * lane) = v;
        }
    }
}

// ----------------------- epilogue: self-loop + bias/relu + bayes + lsm ------
__global__ __launch_bounds__(256) void final_k(const int* __restrict__ flags,
                                               const float* __restrict__ agg,
                                               const float* __restrict__ dis,
                                               const ushort* __restrict__ hb,
                                               const void* __restrict__ gcn_b,
                                               const void* __restrict__ w_mu,
                                               const void* __restrict__ w_ls,
                                               const void* __restrict__ b_mu,
                                               const void* __restrict__ b_ls,
                                               const void* __restrict__ eps_w,
                                               const void* __restrict__ eps_b,
                                               void* __restrict__ out) {
    const int f32f = flags[0];
    const int lane = threadIdx.x & 63;
    const int node = blockIdx.x * 4 + (threadIdx.x >> 6);   // N % 4 == 0

    float2 a2 = *(const float2*)(agg + (size_t)node * H_DIM + 2 * lane);
    float dd = dis[node];
    uint us = *((const uint*)(hb + (size_t)node * H_DIM) + lane);
    float ax = a2.x * dd + __uint_as_float(us << 16) * dd * dd + ldsel(gcn_b, 2 * lane, f32f);
    float ay = a2.y * dd + __uint_as_float(us & 0xFFFF0000u) * dd * dd + ldsel(gcn_b, 2 * lane + 1, f32f);
    ax = fmaxf(ax, 0.f);
    ay = fmaxf(ay, 0.f);

    float p[C_CLS];
#pragma unroll
    for (int c = 0; c < C_CLS; ++c) {
        int i0 = c * H_DIM + 2 * lane;
        float wx = ldsel(w_mu, i0, f32f)     + __expf(ldsel(w_ls, i0, f32f))     * ldsel(eps_w, i0, f32f);
        float wy = ldsel(w_mu, i0 + 1, f32f) + __expf(ldsel(w_ls, i0 + 1, f32f)) * ldsel(eps_w, i0 + 1, f32f);
        p[c] = ax * wx + ay * wy;
    }
#pragma unroll
    for (int off = 32; off >= 1; off >>= 1) {
#pragma unroll
        for (int c = 0; c < C_CLS; ++c) p[c] += __shfl_xor(p[c], off, 64);
    }
#pragma unroll
    for (int c = 0; c < C_CLS; ++c)
        p[c] += ldsel(b_mu, c, f32f) + __expf(ldsel(b_ls, c, f32f)) * ldsel(eps_b, c, f32f);

    float m = p[0];
#pragma unroll
    for (int c = 1; c < C_CLS; ++c) m = fmaxf(m, p[c]);
    float ssum = 0.f;
#pragma unroll
    for (int c = 0; c < C_CLS; ++c) ssum += __expf(p[c] - m);
    float lse = m + __logf(ssum);

    if (lane == 0) {
        if (f32f) {
            float* op = (float*)out + (size_t)node * C_CLS;
            float4 o[4];
#pragma unroll
            for (int c = 0; c < C_CLS; ++c) ((float*)o)[c] = p[c] - lse;
#pragma unroll
            for (int q = 0; q < 4; ++q) ((float4*)op)[q] = o[q];
        } else {
            ushort* op = (ushort*)out + (size_t)node * C_CLS;
            ushort4v o[4];
#pragma unroll
            for (int c = 0; c < C_CLS; ++c) ((ushort*)o)[c] = f2b(p[c] - lse);
#pragma unroll
            for (int q = 0; q < 4; ++q) ((ushort4v*)op)[q] = o[q];
        }
    }
}

// ---------------------------------------------------------------------------
extern "C" void kernel_launch(void* const* d_in, const int* in_sizes, int n_in,
                              void* d_out, int out_size, void* d_ws, size_t ws_size,
                              hipStream_t stream) {
    const int E = in_sizes[1] / 2;

    char* wp = (char*)d_ws;
    auto alloc = [&](size_t bytes) -> char* {
        char* p = wp; wp += (bytes + 511) & ~(size_t)511; return p;
    };
    int*    flags  = (int*)   alloc(64);
    uint*   sinkb  = (uint*)  alloc(64);
    ushort* hb     = (ushort*)alloc((size_t)N_NODES * H_DIM * 2);   // bf16 h
    float*  agg    = (float*) alloc((size_t)N_NODES * H_DIM * 4);   // raw sums
    int*    cnt    = (int*)   alloc((size_t)NBINS * 4);
    int*    offs2  = (int*)   alloc((size_t)(NBINS + 1) * 4);
    int*    cursor = (int*)   alloc((size_t)NBINS * 4);
    int*    bsum   = (int*)   alloc((size_t)SB1 * 4);
    int*    boff   = (int*)   alloc((size_t)SB1 * 4);
    float*  dis    = (float*) alloc((size_t)N_NODES * 4);
    int2*   perm2  = (int2*)  alloc((size_t)E * 8);
    int*    src32  = (int*)   alloc((size_t)E * 4);
    int*    dst32  = (int*)   alloc((size_t)E * 4);

    sniff<<<1, 64, 0, stream>>>((const ushort*)d_in[0], (const int*)d_in[1], flags);
    (void)hipMemsetAsync(cnt, 0, (size_t)NBINS * 4, stream);
    prep<<<(E + 255) / 256, 256, 0, stream>>>(flags, (const int*)d_in[1], src32, dst32, cnt, E);
    scan1<<<SB1, 256, 0, stream>>>(cnt, offs2, bsum, NBINS);
    scan2big<<<1, 512, 0, stream>>>(bsum, boff, SB1);
    scan3big<<<SB1, 256, 0, stream>>>(offs2, boff, cursor, E);
    disk<<<(N_NODES + 255) / 256, 256, 0, stream>>>(offs2, dis);
    build_perm<<<(E + 255) / 256, 256, 0, stream>>>(src32, dst32, dis, cursor, perm2, E);
    gemm_xw<<<(N_NODES + 63) / 64, 256, 0, stream>>>(flags,
                 (const ushort*)d_in[0], (const float*)d_in[0],
                 (const ushort*)d_in[2], (const float*)d_in[2], hb);
    gcn_bucket<<<GBLK, 256, 0, stream>>>(offs2, perm2, hb, agg, sinkb, E);
    final_k<<<N_NODES / 4, 256, 0, stream>>>(flags, agg, dis, hb,
                 d_in[3], d_in[4], d_in[5], d_in[6], d_in[7], d_in[8], d_in[9], (void*)d_out);
}